// Round 3
// baseline (1743.941 us; speedup 1.0000x reference)
//
#include <hip/hip_runtime.h>
#include <hip/hip_bf16.h>
#include <math.h>

typedef __hip_bfloat16 bf16;

// Problem constants (fixed by reference)
#define B_      8
#define S_      2048
#define DIN     1024
#define DSTATE  1024
#define H_      16
#define DH_     64
#define PROJ4   4096   // 4*DSTATE

// Barrier that does NOT drain vmcnt: LDS ordering only. Keeps prefetch loads
// and fire-and-forget stores in flight across the barrier.
#define BARRIER_LGKM() asm volatile("s_waitcnt lgkmcnt(0)\n\ts_barrier" ::: "memory")

// ---------------------------------------------------------------------------
// bf16 <-> f32 helpers (bit-level, RNE for store)
// ---------------------------------------------------------------------------
__device__ __forceinline__ unsigned short f2bf(float f) {
    unsigned int x = __float_as_uint(f);
    x += 0x7FFFu + ((x >> 16) & 1u);   // round-to-nearest-even
    return (unsigned short)(x >> 16);
}

__device__ __forceinline__ float4 load4(const float* p) { return *(const float4*)p; }
__device__ __forceinline__ float4 load4(const bf16* p) {
    uint2 u = *(const uint2*)p;    // 4 bf16 = 8 bytes
    float4 r;
    r.x = __uint_as_float((u.x & 0xFFFFu) << 16);
    r.y = __uint_as_float(u.x & 0xFFFF0000u);
    r.z = __uint_as_float((u.y & 0xFFFFu) << 16);
    r.w = __uint_as_float(u.y & 0xFFFF0000u);
    return r;
}
__device__ __forceinline__ void store4(float* p, float4 v) { *(float4*)p = v; }
__device__ __forceinline__ void store4(bf16* p, float4 v) {
    uint2 u;
    u.x = (unsigned int)f2bf(v.x) | ((unsigned int)f2bf(v.y) << 16);
    u.y = (unsigned int)f2bf(v.z) | ((unsigned int)f2bf(v.w) << 16);
    *(uint2*)p = u;
}

// ---------------------------------------------------------------------------
// MFMA bf16 GEMM (unchanged — recur is this round's target).
// ---------------------------------------------------------------------------
typedef __attribute__((ext_vector_type(8))) short bf16x8;
typedef __attribute__((ext_vector_type(4))) float f32x4;
typedef __attribute__((ext_vector_type(2))) float f32x2;
typedef __attribute__((ext_vector_type(4))) short short4v;

template <typename TA>
__device__ __forceinline__ void load_a4(const TA* p, float out[4]);
template <>
__device__ __forceinline__ void load_a4<float>(const float* p, float out[4]) {
    float4 v = *(const float4*)p;
    out[0] = v.x; out[1] = v.y; out[2] = v.z; out[3] = v.w;
}
template <>
__device__ __forceinline__ void load_a4<bf16>(const bf16* p, float out[4]) {
    float4 v = load4(p);
    out[0] = v.x; out[1] = v.y; out[2] = v.z; out[3] = v.w;
}

template <typename TA, typename TC>
__global__ __launch_bounds__(256) void gemm_mfma(const TA* __restrict__ A,
                                                 const float* __restrict__ Bm,
                                                 TC* __restrict__ C,
                                                 int M, int N, int K, int lda) {
    __shared__ short As[128][40];   // As[m][k], k contiguous
    __shared__ short Bs[128][40];   // Bs[n][k], k contiguous (B transposed)

    const int tid = threadIdx.x;
    const int m0 = blockIdx.y * 128;
    const int n0 = blockIdx.x * 128;

    const int saM = tid >> 1;              // 0..127
    const int saK = (tid & 1) * 16;        // 0 or 16
    const int sbK = tid >> 3;              // 0..31
    const int sbN = (tid & 7) * 16;        // 0..112

    const int wid = tid >> 6;
    const int wx = wid & 1, wy = wid >> 1; // 2x2 wave grid
    const int lane = tid & 63;
    const int c16 = lane & 15;
    const int quad = lane >> 4;

    const TA* Aptr = A + (size_t)(m0 + saM) * lda + saK;
    const float* Bptr = Bm + (size_t)sbK * N + n0 + sbN;

    f32x4 acc[4][4];
    #pragma unroll
    for (int i = 0; i < 4; ++i)
        #pragma unroll
        for (int j = 0; j < 4; ++j) acc[i][j] = (f32x4){0.f, 0.f, 0.f, 0.f};

    float ra[4][4];
    float rb[4][4];
    #pragma unroll
    for (int i = 0; i < 4; ++i) load_a4<TA>(Aptr + i * 4, ra[i]);
    #pragma unroll
    for (int i = 0; i < 4; ++i) {
        float4 v = load4(Bptr + i * 4);
        rb[i][0] = v.x; rb[i][1] = v.y; rb[i][2] = v.z; rb[i][3] = v.w;
    }

    for (int k0 = 0; k0 < K; k0 += 32) {
        __syncthreads();
        #pragma unroll
        for (int i = 0; i < 4; ++i) {
            short4v pk = { (short)f2bf(ra[i][0]), (short)f2bf(ra[i][1]),
                           (short)f2bf(ra[i][2]), (short)f2bf(ra[i][3]) };
            *(short4v*)&As[saM][saK + i * 4] = pk;
        }
        #pragma unroll
        for (int i = 0; i < 4; ++i)
            #pragma unroll
            for (int j = 0; j < 4; ++j)
                Bs[sbN + i * 4 + j][sbK] = (short)f2bf(rb[i][j]);
        __syncthreads();

        if (k0 + 32 < K) {
            #pragma unroll
            for (int i = 0; i < 4; ++i) load_a4<TA>(Aptr + k0 + 32 + i * 4, ra[i]);
            #pragma unroll
            for (int i = 0; i < 4; ++i) {
                float4 v = load4(Bptr + (size_t)(k0 + 32) * N + i * 4);
                rb[i][0] = v.x; rb[i][1] = v.y; rb[i][2] = v.z; rb[i][3] = v.w;
            }
        }

        bf16x8 af[4], bfr[4];
        #pragma unroll
        for (int mt = 0; mt < 4; ++mt)
            af[mt] = *(const bf16x8*)&As[wy * 64 + mt * 16 + c16][quad * 8];
        #pragma unroll
        for (int nt = 0; nt < 4; ++nt)
            bfr[nt] = *(const bf16x8*)&Bs[wx * 64 + nt * 16 + c16][quad * 8];

        #pragma unroll
        for (int mt = 0; mt < 4; ++mt)
            #pragma unroll
            for (int nt = 0; nt < 4; ++nt)
                acc[mt][nt] = __builtin_amdgcn_mfma_f32_16x16x32_bf16(
                    af[mt], bfr[nt], acc[mt][nt], 0, 0, 0);
    }

    #pragma unroll
    for (int mt = 0; mt < 4; ++mt) {
        #pragma unroll
        for (int r = 0; r < 4; ++r) {
            int row = m0 + wy * 64 + mt * 16 + quad * 4 + r;
            TC* cp = C + (size_t)row * N + n0 + wx * 64;
            #pragma unroll
            for (int nt = 0; nt < 4; ++nt)
                cp[nt * 16 + c16] = (TC)acc[mt][nt][r];
        }
    }
}

// ---------------------------------------------------------------------------
// Recurrence v4: 4 waves per (b,h) chain, v0's sync structure FIXED.
//  - Each wave holds full h replicated (lane e owns h[e]); broadcast of h
//    and rh is v_readlane within the wave — NO LDS round trip for either.
//  - LDS only for the two partial-sum exchanges (lgkm-only barriers).
//  - Weights: 48 NAMED scalar floats per lane (d-slice of 16 x 3 matrices) —
//    cannot spill (v0's VGPR_Count=36 proved its arrays spilled to scratch;
//    that, not the barriers, was its 1970cy/step).
//  - Symmetric prefetch: EVERY wave loads its own x-row copies each step
//    (same cache lines -> L2 absorbs), so all waves run identical schedules
//    and arrive at barriers together (no turn-skew).
// Estimated critical path ~635 cy/step vs measured 1290 for 1-wave v3.
// ---------------------------------------------------------------------------
__device__ __forceinline__ float lane_bcast(float v, int lane) {
    return __int_as_float(__builtin_amdgcn_readlane(__float_as_int(v), lane));
}

#define RPT16(M) M(0) M(1) M(2) M(3) M(4) M(5) M(6) M(7) \
                 M(8) M(9) M(10) M(11) M(12) M(13) M(14) M(15)

__global__ __launch_bounds__(256, 1) void recur_kernel(bf16* __restrict__ proj,
                                                       const float* __restrict__ sw) {
    const int tid = threadIdx.x;
    const int e = tid & 63;
    const int w = __builtin_amdgcn_readfirstlane(tid >> 6);   // 0..3
    const int d0 = w << 4;                                    // wave's d-slice base
    const int bh = blockIdx.x;              // 0..127
    const int b = bh >> 4;
    const int h = bh & 15;

    __shared__ float2 part_rf[4][64];   // (r,f) partials per wave
    __shared__ float  part_c[4][64];    // c partials per wave

    // Weight slice for this wave/lane: W[h][d0+i][e], i=0..15.
    const float* Wc_p = sw + (size_t)h * 4096 + (size_t)d0 * 64 + e;
    const float* Wf_p = Wc_p + (size_t)16 * 4096;
    const float* Wr_p = Wc_p + (size_t)32 * 4096;

    // 48 named scalar weights — guaranteed register-resident.
    #define DECLW(i) float wc##i, wf##i, wr##i;
    RPT16(DECLW)
    #undef DECLW
    #define LOADW(i) wc##i = Wc_p[(i) * 64]; \
                     wf##i = Wf_p[(i) * 64]; \
                     wr##i = Wr_p[(i) * 64];
    RPT16(LOADW)
    #undef LOADW

    bf16* xi_p = proj + (size_t)b * S_ * PROJ4 + h * 64 + e;   // cols [0:1024)

    // Register prefetch ring, 4 steps deep, every wave its own copy.
    f32x4 rxi, rxf, rxr;
    #define PRELOAD(U) { const bf16* p = xi_p + (size_t)(U) * PROJ4; \
        rxi[U] = __bfloat162float(p[0]); \
        rxf[U] = __bfloat162float(p[1024]); \
        rxr[U] = __bfloat162float(p[2048]); }
    PRELOAD(0) PRELOAD(1) PRELOAD(2) PRELOAD(3)
    #undef PRELOAD

    float hreg = 0.0f;   // lane e holds h[e]; identical in all 4 waves

    const bf16* ld = xi_p + (size_t)4 * PROJ4;  // refill ptr (t+4)
    bf16*       st = xi_p;                      // store ptr (t)

    // P1 term: broadcast h[d0+i], accumulate r and f gate partials.
    #define P1T(i, A) { float hb = lane_bcast(hreg, d0 + (i)); \
        aR##A = fmaf(hb, wr##i, aR##A); \
        aF##A = fmaf(hb, wf##i, aF##A); }
    // P2 term: broadcast rh[d0+i], accumulate c partial.
    #define P2T(i, A) { float qb = lane_bcast(rh, d0 + (i)); \
        aC##A = fmaf(qb, wc##i, aC##A); }

    #define STEP(U, REFILL) { \
        float xi0 = rxi[U], xf0 = rxf[U], xr0 = rxr[U]; \
        if (REFILL) { \
            const bf16* p = ld + (size_t)(U) * PROJ4; \
            rxi[U] = __bfloat162float(p[0]); \
            rxf[U] = __bfloat162float(p[1024]); \
            rxr[U] = __bfloat162float(p[2048]); \
        } \
        float aR0 = 0.f, aR1 = 0.f, aF0 = 0.f, aF1 = 0.f; \
        P1T(0,0)  P1T(1,1)  P1T(2,0)  P1T(3,1) \
        P1T(4,0)  P1T(5,1)  P1T(6,0)  P1T(7,1) \
        P1T(8,0)  P1T(9,1)  P1T(10,0) P1T(11,1) \
        P1T(12,0) P1T(13,1) P1T(14,0) P1T(15,1) \
        part_rf[w][e] = make_float2(aR0 + aR1, aF0 + aF1); \
        BARRIER_LGKM(); \
        float2 p0 = part_rf[0][e], p1 = part_rf[1][e]; \
        float2 p2 = part_rf[2][e], p3 = part_rf[3][e]; \
        float sr = xr0 + (p0.x + p1.x) + (p2.x + p3.x); \
        float sf = xf0 + (p0.y + p1.y) + (p2.y + p3.y); \
        float r = 1.f / (1.f + __expf(-sr)); \
        float f = 1.f / (1.f + __expf(-sf)); \
        float rh = r * hreg; \
        float aC0 = 0.f, aC1 = 0.f; \
        P2T(0,0)  P2T(1,1)  P2T(2,0)  P2T(3,1) \
        P2T(4,0)  P2T(5,1)  P2T(6,0)  P2T(7,1) \
        P2T(8,0)  P2T(9,1)  P2T(10,0) P2T(11,1) \
        P2T(12,0) P2T(13,1) P2T(14,0) P2T(15,1) \
        part_c[w][e] = aC0 + aC1; \
        BARRIER_LGKM(); \
        float sc = xi0 + (part_c[0][e] + part_c[1][e]) \
                       + (part_c[2][e] + part_c[3][e]); \
        sc = fminf(fmaxf(sc, -15.f), 15.f); \
        float ex = __expf(-2.f * sc); \
        float cc = (1.f - ex) / (1.f + ex); \
        hreg = f * hreg + (1.f - f) * cc; \
        if (w == (U)) st[(size_t)(U) * PROJ4] = __float2bfloat16(hreg); \
    }

    for (int t0 = 0; t0 < S_ - 4; t0 += 4) {
        STEP(0, 1) STEP(1, 1) STEP(2, 1) STEP(3, 1)
        ld += (size_t)4 * PROJ4;
        st += (size_t)4 * PROJ4;
    }
    STEP(0, 0) STEP(1, 0) STEP(2, 0) STEP(3, 0)

    #undef STEP
    #undef P1T
    #undef P2T
}

// ---------------------------------------------------------------------------
// Gated RMSNorm in place over proj cols [0:1024).
// ---------------------------------------------------------------------------
__global__ __launch_bounds__(256) void gate_norm_kernel(bf16* __restrict__ proj,
                                                        const float* __restrict__ nw) {
    const int row = blockIdx.x;
    const int tid = threadIdx.x;
    __shared__ float red[4];

    bf16* hp = proj + (size_t)row * PROJ4;
    const bf16* gp = hp + 3 * DSTATE;

    float4 hv = load4(hp + tid * 4);
    float4 gv = load4(gp + tid * 4);

    float v0 = hv.x * (gv.x / (1.f + __expf(-gv.x)));
    float v1 = hv.y * (gv.y / (1.f + __expf(-gv.y)));
    float v2 = hv.z * (gv.z / (1.f + __expf(-gv.z)));
    float v3 = hv.w * (gv.w / (1.f + __expf(-gv.w)));

    float ss = v0 * v0 + v1 * v1 + v2 * v2 + v3 * v3;
    #pragma unroll
    for (int mask = 32; mask >= 1; mask >>= 1)
        ss += __shfl_xor(ss, mask, 64);

    const int wid = tid >> 6;
    if ((tid & 63) == 0) red[wid] = ss;
    __syncthreads();
    float tot = red[0] + red[1] + red[2] + red[3];
    float scale = rsqrtf(tot * (1.0f / (float)DSTATE) + 1e-6f);

    float4 nv = *(const float4*)(nw + tid * 4);
    float4 y;
    y.x = v0 * scale * nv.x;
    y.y = v1 * scale * nv.y;
    y.z = v2 * scale * nv.z;
    y.w = v3 * scale * nv.w;
    store4(hp + tid * 4, y);
}

// ---------------------------------------------------------------------------
extern "C" void kernel_launch(void* const* d_in, const int* in_sizes, int n_in,
                              void* d_out, int out_size, void* d_ws, size_t ws_size,
                              hipStream_t stream) {
    const float* x     = (const float*)d_in[0];   // [B,S,DIN]
    const float* w_in  = (const float*)d_in[1];   // [DIN, 4*DSTATE]
    const float* sw    = (const float*)d_in[2];   // [3H, DH, DH]
    const float* nw    = (const float*)d_in[3];   // [DSTATE]
    const float* w_out = (const float*)d_in[4];   // [DSTATE, DOUT]
    float* out = (float*)d_out;

    bf16* proj = (bf16*)d_ws;    // [B*S, 4096] bf16 = 134 MB (only ws use)

    // 1) input projection GEMM (MFMA bf16): [16384,1024] @ [1024,4096] -> bf16
    dim3 g1(PROJ4 / 128, (B_ * S_) / 128);
    gemm_mfma<float, bf16><<<g1, 256, 0, stream>>>(x, w_in, proj,
                                                   B_ * S_, PROJ4, DIN, DIN);

    // 2) sequential gated recurrence: 4 waves/chain, readlane broadcasts,
    //    LDS only for partial exchanges
    recur_kernel<<<128, 256, 0, stream>>>(proj, sw);

    // 3) gate + rmsnorm in place over cols 0:1024
    gate_norm_kernel<<<B_ * S_, 256, 0, stream>>>(proj, nw);

    // 4) output projection GEMM (MFMA bf16): y(bf16, lda=4096) @ [1024,1024] -> f32
    dim3 g2(DSTATE / 128, (B_ * S_) / 128);
    gemm_mfma<bf16, float><<<g2, 256, 0, stream>>>(proj, w_out, out,
                                                   B_ * S_, DSTATE, DSTATE, PROJ4);
}

// Round 4
// 1732.296 us; speedup vs baseline: 1.0067x; 1.0067x over previous
//
#include <hip/hip_runtime.h>
#include <hip/hip_bf16.h>
#include <math.h>

typedef __hip_bfloat16 bf16;

// Problem constants (fixed by reference)
#define B_      8
#define S_      2048
#define DIN     1024
#define DSTATE  1024
#define H_      16
#define DH_     64
#define PROJ4   4096   // 4*DSTATE

// Barrier that does NOT drain vmcnt: LDS ordering only. Keeps prefetch loads
// and fire-and-forget stores in flight across the barrier.
#define BARRIER_LGKM() asm volatile("s_waitcnt lgkmcnt(0)\n\ts_barrier" ::: "memory")

// ---------------------------------------------------------------------------
// bf16 <-> f32 helpers (bit-level, RNE for store)
// ---------------------------------------------------------------------------
__device__ __forceinline__ unsigned short f2bf(float f) {
    unsigned int x = __float_as_uint(f);
    x += 0x7FFFu + ((x >> 16) & 1u);   // round-to-nearest-even
    return (unsigned short)(x >> 16);
}

__device__ __forceinline__ float4 load4(const float* p) { return *(const float4*)p; }
__device__ __forceinline__ float4 load4(const bf16* p) {
    uint2 u = *(const uint2*)p;    // 4 bf16 = 8 bytes
    float4 r;
    r.x = __uint_as_float((u.x & 0xFFFFu) << 16);
    r.y = __uint_as_float(u.x & 0xFFFF0000u);
    r.z = __uint_as_float((u.y & 0xFFFFu) << 16);
    r.w = __uint_as_float(u.y & 0xFFFF0000u);
    return r;
}
__device__ __forceinline__ void store4(float* p, float4 v) { *(float4*)p = v; }
__device__ __forceinline__ void store4(bf16* p, float4 v) {
    uint2 u;
    u.x = (unsigned int)f2bf(v.x) | ((unsigned int)f2bf(v.y) << 16);
    u.y = (unsigned int)f2bf(v.z) | ((unsigned int)f2bf(v.w) << 16);
    *(uint2*)p = u;
}

// ---------------------------------------------------------------------------
// MFMA bf16 GEMM (unchanged — recur is this round's target).
// ---------------------------------------------------------------------------
typedef __attribute__((ext_vector_type(8))) short bf16x8;
typedef __attribute__((ext_vector_type(4))) float f32x4;
typedef __attribute__((ext_vector_type(2))) float f32x2;
typedef __attribute__((ext_vector_type(4))) short short4v;

template <typename TA>
__device__ __forceinline__ void load_a4(const TA* p, float out[4]);
template <>
__device__ __forceinline__ void load_a4<float>(const float* p, float out[4]) {
    float4 v = *(const float4*)p;
    out[0] = v.x; out[1] = v.y; out[2] = v.z; out[3] = v.w;
}
template <>
__device__ __forceinline__ void load_a4<bf16>(const bf16* p, float out[4]) {
    float4 v = load4(p);
    out[0] = v.x; out[1] = v.y; out[2] = v.z; out[3] = v.w;
}

template <typename TA, typename TC>
__global__ __launch_bounds__(256) void gemm_mfma(const TA* __restrict__ A,
                                                 const float* __restrict__ Bm,
                                                 TC* __restrict__ C,
                                                 int M, int N, int K, int lda) {
    __shared__ short As[128][40];   // As[m][k], k contiguous
    __shared__ short Bs[128][40];   // Bs[n][k], k contiguous (B transposed)

    const int tid = threadIdx.x;
    const int m0 = blockIdx.y * 128;
    const int n0 = blockIdx.x * 128;

    const int saM = tid >> 1;              // 0..127
    const int saK = (tid & 1) * 16;        // 0 or 16
    const int sbK = tid >> 3;              // 0..31
    const int sbN = (tid & 7) * 16;        // 0..112

    const int wid = tid >> 6;
    const int wx = wid & 1, wy = wid >> 1; // 2x2 wave grid
    const int lane = tid & 63;
    const int c16 = lane & 15;
    const int quad = lane >> 4;

    const TA* Aptr = A + (size_t)(m0 + saM) * lda + saK;
    const float* Bptr = Bm + (size_t)sbK * N + n0 + sbN;

    f32x4 acc[4][4];
    #pragma unroll
    for (int i = 0; i < 4; ++i)
        #pragma unroll
        for (int j = 0; j < 4; ++j) acc[i][j] = (f32x4){0.f, 0.f, 0.f, 0.f};

    float ra[4][4];
    float rb[4][4];
    #pragma unroll
    for (int i = 0; i < 4; ++i) load_a4<TA>(Aptr + i * 4, ra[i]);
    #pragma unroll
    for (int i = 0; i < 4; ++i) {
        float4 v = load4(Bptr + i * 4);
        rb[i][0] = v.x; rb[i][1] = v.y; rb[i][2] = v.z; rb[i][3] = v.w;
    }

    for (int k0 = 0; k0 < K; k0 += 32) {
        __syncthreads();
        #pragma unroll
        for (int i = 0; i < 4; ++i) {
            short4v pk = { (short)f2bf(ra[i][0]), (short)f2bf(ra[i][1]),
                           (short)f2bf(ra[i][2]), (short)f2bf(ra[i][3]) };
            *(short4v*)&As[saM][saK + i * 4] = pk;
        }
        #pragma unroll
        for (int i = 0; i < 4; ++i)
            #pragma unroll
            for (int j = 0; j < 4; ++j)
                Bs[sbN + i * 4 + j][sbK] = (short)f2bf(rb[i][j]);
        __syncthreads();

        if (k0 + 32 < K) {
            #pragma unroll
            for (int i = 0; i < 4; ++i) load_a4<TA>(Aptr + k0 + 32 + i * 4, ra[i]);
            #pragma unroll
            for (int i = 0; i < 4; ++i) {
                float4 v = load4(Bptr + (size_t)(k0 + 32) * N + i * 4);
                rb[i][0] = v.x; rb[i][1] = v.y; rb[i][2] = v.z; rb[i][3] = v.w;
            }
        }

        bf16x8 af[4], bfr[4];
        #pragma unroll
        for (int mt = 0; mt < 4; ++mt)
            af[mt] = *(const bf16x8*)&As[wy * 64 + mt * 16 + c16][quad * 8];
        #pragma unroll
        for (int nt = 0; nt < 4; ++nt)
            bfr[nt] = *(const bf16x8*)&Bs[wx * 64 + nt * 16 + c16][quad * 8];

        #pragma unroll
        for (int mt = 0; mt < 4; ++mt)
            #pragma unroll
            for (int nt = 0; nt < 4; ++nt)
                acc[mt][nt] = __builtin_amdgcn_mfma_f32_16x16x32_bf16(
                    af[mt], bfr[nt], acc[mt][nt], 0, 0, 0);
    }

    #pragma unroll
    for (int mt = 0; mt < 4; ++mt) {
        #pragma unroll
        for (int r = 0; r < 4; ++r) {
            int row = m0 + wy * 64 + mt * 16 + quad * 4 + r;
            TC* cp = C + (size_t)row * N + n0 + wx * 64;
            #pragma unroll
            for (int nt = 0; nt < 4; ++nt)
                cp[nt * 16 + c16] = (TC)acc[mt][nt][r];
        }
    }
}

// ---------------------------------------------------------------------------
// Recurrence v5 = v4 structure + forced weight residency.
//  Evidence trail: R1 VGPR=124 (arrays spilled), R2 VGPR=128 (= 512/4: RA
//  targeted default 4-waves/EU budget, launch_bounds 2nd arg not effective),
//  R3 VGPR=44 < 48 named weights (LICM/RA re-loaded weights per step).
//  Fixes:
//   (a) amdgpu_waves_per_eu(1,1): all pressure heuristics now see the full
//       512-VGPR budget (we truly run 1 wave/SIMD: 128 blocks x 4 waves).
//   (b) asm volatile "+v" pin on each weight after load: the loop consumes
//       opaque asm outputs — cannot be rematerialized by re-loading.
// ---------------------------------------------------------------------------
__device__ __forceinline__ float lane_bcast(float v, int lane) {
    return __int_as_float(__builtin_amdgcn_readlane(__float_as_int(v), lane));
}

#define RPT16(M) M(0) M(1) M(2) M(3) M(4) M(5) M(6) M(7) \
                 M(8) M(9) M(10) M(11) M(12) M(13) M(14) M(15)

__global__ __launch_bounds__(256, 1)
__attribute__((amdgpu_waves_per_eu(1, 1)))
void recur_kernel(bf16* __restrict__ proj, const float* __restrict__ sw) {
    const int tid = threadIdx.x;
    const int e = tid & 63;
    const int w = __builtin_amdgcn_readfirstlane(tid >> 6);   // 0..3
    const int d0 = w << 4;                                    // wave's d-slice base
    const int bh = blockIdx.x;              // 0..127
    const int b = bh >> 4;
    const int h = bh & 15;

    __shared__ float2 part_rf[4][64];   // (r,f) partials per wave
    __shared__ float  part_c[4][64];    // c partials per wave

    // Weight slice for this wave/lane: W[h][d0+i][e], i=0..15.
    const float* Wc_p = sw + (size_t)h * 4096 + (size_t)d0 * 64 + e;
    const float* Wf_p = Wc_p + (size_t)16 * 4096;
    const float* Wr_p = Wc_p + (size_t)32 * 4096;

    // 48 named scalar weights, pinned into VGPRs (opaque to remat/sink).
    #define DECLW(i) float wc##i, wf##i, wr##i;
    RPT16(DECLW)
    #undef DECLW
    #define LOADW(i) wc##i = Wc_p[(i) * 64]; \
                     wf##i = Wf_p[(i) * 64]; \
                     wr##i = Wr_p[(i) * 64];
    RPT16(LOADW)
    #undef LOADW
    #define PINW(i) asm volatile("" : "+v"(wc##i), "+v"(wf##i), "+v"(wr##i));
    RPT16(PINW)
    #undef PINW

    bf16* xi_p = proj + (size_t)b * S_ * PROJ4 + h * 64 + e;   // cols [0:1024)

    // Register prefetch ring, 4 steps deep, every wave its own copy.
    f32x4 rxi, rxf, rxr;
    #define PRELOAD(U) { const bf16* p = xi_p + (size_t)(U) * PROJ4; \
        rxi[U] = __bfloat162float(p[0]); \
        rxf[U] = __bfloat162float(p[1024]); \
        rxr[U] = __bfloat162float(p[2048]); }
    PRELOAD(0) PRELOAD(1) PRELOAD(2) PRELOAD(3)
    #undef PRELOAD

    float hreg = 0.0f;   // lane e holds h[e]; identical in all 4 waves

    const bf16* ld = xi_p + (size_t)4 * PROJ4;  // refill ptr (t+4)
    bf16*       st = xi_p;                      // store ptr (t)

    // P1 term: broadcast h[d0+i], accumulate r and f gate partials.
    #define P1T(i, A) { float hb = lane_bcast(hreg, d0 + (i)); \
        aR##A = fmaf(hb, wr##i, aR##A); \
        aF##A = fmaf(hb, wf##i, aF##A); }
    // P2 term: broadcast rh[d0+i], accumulate c partial.
    #define P2T(i, A) { float qb = lane_bcast(rh, d0 + (i)); \
        aC##A = fmaf(qb, wc##i, aC##A); }

    #define STEP(U, REFILL) { \
        float xi0 = rxi[U], xf0 = rxf[U], xr0 = rxr[U]; \
        if (REFILL) { \
            const bf16* p = ld + (size_t)(U) * PROJ4; \
            rxi[U] = __bfloat162float(p[0]); \
            rxf[U] = __bfloat162float(p[1024]); \
            rxr[U] = __bfloat162float(p[2048]); \
        } \
        float aR0 = 0.f, aR1 = 0.f, aF0 = 0.f, aF1 = 0.f; \
        P1T(0,0)  P1T(1,1)  P1T(2,0)  P1T(3,1) \
        P1T(4,0)  P1T(5,1)  P1T(6,0)  P1T(7,1) \
        P1T(8,0)  P1T(9,1)  P1T(10,0) P1T(11,1) \
        P1T(12,0) P1T(13,1) P1T(14,0) P1T(15,1) \
        part_rf[w][e] = make_float2(aR0 + aR1, aF0 + aF1); \
        BARRIER_LGKM(); \
        float2 p0 = part_rf[0][e], p1 = part_rf[1][e]; \
        float2 p2 = part_rf[2][e], p3 = part_rf[3][e]; \
        float sr = xr0 + (p0.x + p1.x) + (p2.x + p3.x); \
        float sf = xf0 + (p0.y + p1.y) + (p2.y + p3.y); \
        float r = 1.f / (1.f + __expf(-sr)); \
        float f = 1.f / (1.f + __expf(-sf)); \
        float rh = r * hreg; \
        float aC0 = 0.f, aC1 = 0.f; \
        P2T(0,0)  P2T(1,1)  P2T(2,0)  P2T(3,1) \
        P2T(4,0)  P2T(5,1)  P2T(6,0)  P2T(7,1) \
        P2T(8,0)  P2T(9,1)  P2T(10,0) P2T(11,1) \
        P2T(12,0) P2T(13,1) P2T(14,0) P2T(15,1) \
        part_c[w][e] = aC0 + aC1; \
        BARRIER_LGKM(); \
        float sc = xi0 + (part_c[0][e] + part_c[1][e]) \
                       + (part_c[2][e] + part_c[3][e]); \
        sc = fminf(fmaxf(sc, -15.f), 15.f); \
        float ex = __expf(-2.f * sc); \
        float cc = (1.f - ex) / (1.f + ex); \
        hreg = f * hreg + (1.f - f) * cc; \
        if (w == (U)) st[(size_t)(U) * PROJ4] = __float2bfloat16(hreg); \
    }

    for (int t0 = 0; t0 < S_ - 4; t0 += 4) {
        STEP(0, 1) STEP(1, 1) STEP(2, 1) STEP(3, 1)
        ld += (size_t)4 * PROJ4;
        st += (size_t)4 * PROJ4;
    }
    STEP(0, 0) STEP(1, 0) STEP(2, 0) STEP(3, 0)

    #undef STEP
    #undef P1T
    #undef P2T
}

// ---------------------------------------------------------------------------
// Gated RMSNorm in place over proj cols [0:1024).
// ---------------------------------------------------------------------------
__global__ __launch_bounds__(256) void gate_norm_kernel(bf16* __restrict__ proj,
                                                        const float* __restrict__ nw) {
    const int row = blockIdx.x;
    const int tid = threadIdx.x;
    __shared__ float red[4];

    bf16* hp = proj + (size_t)row * PROJ4;
    const bf16* gp = hp + 3 * DSTATE;

    float4 hv = load4(hp + tid * 4);
    float4 gv = load4(gp + tid * 4);

    float v0 = hv.x * (gv.x / (1.f + __expf(-gv.x)));
    float v1 = hv.y * (gv.y / (1.f + __expf(-gv.y)));
    float v2 = hv.z * (gv.z / (1.f + __expf(-gv.z)));
    float v3 = hv.w * (gv.w / (1.f + __expf(-gv.w)));

    float ss = v0 * v0 + v1 * v1 + v2 * v2 + v3 * v3;
    #pragma unroll
    for (int mask = 32; mask >= 1; mask >>= 1)
        ss += __shfl_xor(ss, mask, 64);

    const int wid = tid >> 6;
    if ((tid & 63) == 0) red[wid] = ss;
    __syncthreads();
    float tot = red[0] + red[1] + red[2] + red[3];
    float scale = rsqrtf(tot * (1.0f / (float)DSTATE) + 1e-6f);

    float4 nv = *(const float4*)(nw + tid * 4);
    float4 y;
    y.x = v0 * scale * nv.x;
    y.y = v1 * scale * nv.y;
    y.z = v2 * scale * nv.z;
    y.w = v3 * scale * nv.w;
    store4(hp + tid * 4, y);
}

// ---------------------------------------------------------------------------
extern "C" void kernel_launch(void* const* d_in, const int* in_sizes, int n_in,
                              void* d_out, int out_size, void* d_ws, size_t ws_size,
                              hipStream_t stream) {
    const float* x     = (const float*)d_in[0];   // [B,S,DIN]
    const float* w_in  = (const float*)d_in[1];   // [DIN, 4*DSTATE]
    const float* sw    = (const float*)d_in[2];   // [3H, DH, DH]
    const float* nw    = (const float*)d_in[3];   // [DSTATE]
    const float* w_out = (const float*)d_in[4];   // [DSTATE, DOUT]
    float* out = (float*)d_out;

    bf16* proj = (bf16*)d_ws;    // [B*S, 4096] bf16 = 134 MB (only ws use)

    // 1) input projection GEMM (MFMA bf16): [16384,1024] @ [1024,4096] -> bf16
    dim3 g1(PROJ4 / 128, (B_ * S_) / 128);
    gemm_mfma<float, bf16><<<g1, 256, 0, stream>>>(x, w_in, proj,
                                                   B_ * S_, PROJ4, DIN, DIN);

    // 2) sequential gated recurrence: 4 waves/chain, pinned weights
    recur_kernel<<<128, 256, 0, stream>>>(proj, sw);

    // 3) gate + rmsnorm in place over cols 0:1024
    gate_norm_kernel<<<B_ * S_, 256, 0, stream>>>(proj, nw);

    // 4) output projection GEMM (MFMA bf16): y(bf16, lda=4096) @ [1024,1024] -> f32
    dim3 g2(DSTATE / 128, (B_ * S_) / 128);
    gemm_mfma<bf16, float><<<g2, 256, 0, stream>>>(proj, w_out, out,
                                                   B_ * S_, DSTATE, DSTATE, PROJ4);
}

// Round 5
// 1708.639 us; speedup vs baseline: 1.0207x; 1.0138x over previous
//
#include <hip/hip_runtime.h>
#include <hip/hip_bf16.h>
#include <math.h>

typedef __hip_bfloat16 bf16;

// Problem constants (fixed by reference)
#define B_      8
#define S_      2048
#define DIN     1024
#define DSTATE  1024
#define H_      16
#define DH_     64
#define PROJ4   4096   // 4*DSTATE

// Barrier that does NOT drain vmcnt: LDS ordering only. Keeps prefetch loads
// and fire-and-forget stores in flight across the barrier.
#define BARRIER_LGKM() asm volatile("s_waitcnt lgkmcnt(0)\n\ts_barrier" ::: "memory")

// ---------------------------------------------------------------------------
// bf16 <-> f32 helpers (bit-level, RNE for store)
// ---------------------------------------------------------------------------
__device__ __forceinline__ unsigned short f2bf(float f) {
    unsigned int x = __float_as_uint(f);
    x += 0x7FFFu + ((x >> 16) & 1u);   // round-to-nearest-even
    return (unsigned short)(x >> 16);
}

__device__ __forceinline__ float4 load4(const float* p) { return *(const float4*)p; }
__device__ __forceinline__ float4 load4(const bf16* p) {
    uint2 u = *(const uint2*)p;    // 4 bf16 = 8 bytes
    float4 r;
    r.x = __uint_as_float((u.x & 0xFFFFu) << 16);
    r.y = __uint_as_float(u.x & 0xFFFF0000u);
    r.z = __uint_as_float((u.y & 0xFFFFu) << 16);
    r.w = __uint_as_float(u.y & 0xFFFF0000u);
    return r;
}
__device__ __forceinline__ void store4(float* p, float4 v) { *(float4*)p = v; }
__device__ __forceinline__ void store4(bf16* p, float4 v) {
    uint2 u;
    u.x = (unsigned int)f2bf(v.x) | ((unsigned int)f2bf(v.y) << 16);
    u.y = (unsigned int)f2bf(v.z) | ((unsigned int)f2bf(v.w) << 16);
    *(uint2*)p = u;
}

// ---------------------------------------------------------------------------
// MFMA bf16 GEMM (unchanged — recur is this round's target).
// ---------------------------------------------------------------------------
typedef __attribute__((ext_vector_type(8))) short bf16x8;
typedef __attribute__((ext_vector_type(4))) float f32x4;
typedef __attribute__((ext_vector_type(2))) float f32x2;
typedef __attribute__((ext_vector_type(4))) short short4v;

template <typename TA>
__device__ __forceinline__ void load_a4(const TA* p, float out[4]);
template <>
__device__ __forceinline__ void load_a4<float>(const float* p, float out[4]) {
    float4 v = *(const float4*)p;
    out[0] = v.x; out[1] = v.y; out[2] = v.z; out[3] = v.w;
}
template <>
__device__ __forceinline__ void load_a4<bf16>(const bf16* p, float out[4]) {
    float4 v = load4(p);
    out[0] = v.x; out[1] = v.y; out[2] = v.z; out[3] = v.w;
}

template <typename TA, typename TC>
__global__ __launch_bounds__(256) void gemm_mfma(const TA* __restrict__ A,
                                                 const float* __restrict__ Bm,
                                                 TC* __restrict__ C,
                                                 int M, int N, int K, int lda) {
    __shared__ short As[128][40];   // As[m][k], k contiguous
    __shared__ short Bs[128][40];   // Bs[n][k], k contiguous (B transposed)

    const int tid = threadIdx.x;
    const int m0 = blockIdx.y * 128;
    const int n0 = blockIdx.x * 128;

    const int saM = tid >> 1;              // 0..127
    const int saK = (tid & 1) * 16;        // 0 or 16
    const int sbK = tid >> 3;              // 0..31
    const int sbN = (tid & 7) * 16;        // 0..112

    const int wid = tid >> 6;
    const int wx = wid & 1, wy = wid >> 1; // 2x2 wave grid
    const int lane = tid & 63;
    const int c16 = lane & 15;
    const int quad = lane >> 4;

    const TA* Aptr = A + (size_t)(m0 + saM) * lda + saK;
    const float* Bptr = Bm + (size_t)sbK * N + n0 + sbN;

    f32x4 acc[4][4];
    #pragma unroll
    for (int i = 0; i < 4; ++i)
        #pragma unroll
        for (int j = 0; j < 4; ++j) acc[i][j] = (f32x4){0.f, 0.f, 0.f, 0.f};

    float ra[4][4];
    float rb[4][4];
    #pragma unroll
    for (int i = 0; i < 4; ++i) load_a4<TA>(Aptr + i * 4, ra[i]);
    #pragma unroll
    for (int i = 0; i < 4; ++i) {
        float4 v = load4(Bptr + i * 4);
        rb[i][0] = v.x; rb[i][1] = v.y; rb[i][2] = v.z; rb[i][3] = v.w;
    }

    for (int k0 = 0; k0 < K; k0 += 32) {
        __syncthreads();
        #pragma unroll
        for (int i = 0; i < 4; ++i) {
            short4v pk = { (short)f2bf(ra[i][0]), (short)f2bf(ra[i][1]),
                           (short)f2bf(ra[i][2]), (short)f2bf(ra[i][3]) };
            *(short4v*)&As[saM][saK + i * 4] = pk;
        }
        #pragma unroll
        for (int i = 0; i < 4; ++i)
            #pragma unroll
            for (int j = 0; j < 4; ++j)
                Bs[sbN + i * 4 + j][sbK] = (short)f2bf(rb[i][j]);
        __syncthreads();

        if (k0 + 32 < K) {
            #pragma unroll
            for (int i = 0; i < 4; ++i) load_a4<TA>(Aptr + k0 + 32 + i * 4, ra[i]);
            #pragma unroll
            for (int i = 0; i < 4; ++i) {
                float4 v = load4(Bptr + (size_t)(k0 + 32) * N + i * 4);
                rb[i][0] = v.x; rb[i][1] = v.y; rb[i][2] = v.z; rb[i][3] = v.w;
            }
        }

        bf16x8 af[4], bfr[4];
        #pragma unroll
        for (int mt = 0; mt < 4; ++mt)
            af[mt] = *(const bf16x8*)&As[wy * 64 + mt * 16 + c16][quad * 8];
        #pragma unroll
        for (int nt = 0; nt < 4; ++nt)
            bfr[nt] = *(const bf16x8*)&Bs[wx * 64 + nt * 16 + c16][quad * 8];

        #pragma unroll
        for (int mt = 0; mt < 4; ++mt)
            #pragma unroll
            for (int nt = 0; nt < 4; ++nt)
                acc[mt][nt] = __builtin_amdgcn_mfma_f32_16x16x32_bf16(
                    af[mt], bfr[nt], acc[mt][nt], 0, 0, 0);
    }

    #pragma unroll
    for (int mt = 0; mt < 4; ++mt) {
        #pragma unroll
        for (int r = 0; r < 4; ++r) {
            int row = m0 + wy * 64 + mt * 16 + quad * 4 + r;
            TC* cp = C + (size_t)row * N + n0 + wx * 64;
            #pragma unroll
            for (int nt = 0; nt < 4; ++nt)
                cp[nt * 16 + c16] = (TC)acc[mt][nt][r];
        }
    }
}

// ---------------------------------------------------------------------------
// Recurrence v6 = v5 + LDS occupancy-forcing pad.
//  Evidence trail: R3/R4 identical (VGPR=44 < 48 named weights) despite asm
//  pins + waves_per_eu(1,1) — the backend's register-pressure target is
//  derived from achievable OCCUPANCY, and neither attribute moved it. But
//  occupancy is also bounded by LDS: a ~63 KB static LDS block caps the CU
//  at 2 blocks -> 2 waves/EU -> VGPR budget 256, removing every motive to
//  sink/spill the 48 loop-invariant weights. Runtime-free: 128 blocks on
//  256 CUs already run 1 block/CU.
//  Disambiguates: VGPR jumps + time drops => spill was real.
//                 VGPR jumps + time flat  => weights were resident (AGPR),
//                                            structure-bound -> MFMA next.
//                 VGPR flat               => RA target immovable -> MFMA
//                                            under 64-reg budget next.
// ---------------------------------------------------------------------------
__device__ __forceinline__ float lane_bcast(float v, int lane) {
    return __int_as_float(__builtin_amdgcn_readlane(__float_as_int(v), lane));
}

#define RPT16(M) M(0) M(1) M(2) M(3) M(4) M(5) M(6) M(7) \
                 M(8) M(9) M(10) M(11) M(12) M(13) M(14) M(15)

__global__ __launch_bounds__(256, 1)
__attribute__((amdgpu_waves_per_eu(1, 2)))
void recur_kernel(bf16* __restrict__ proj, const float* __restrict__ sw) {
    const int tid = threadIdx.x;
    const int e = tid & 63;
    const int w = __builtin_amdgcn_readfirstlane(tid >> 6);   // 0..3
    const int d0 = w << 4;                                    // wave's d-slice base
    const int bh = blockIdx.x;              // 0..127
    const int b = bh >> 4;
    const int h = bh & 15;

    __shared__ float2 part_rf[4][64];   // (r,f) partials per wave
    __shared__ float  part_c[4][64];    // c partials per wave

    // Occupancy-forcing pad: ~60 KB static LDS (total ~63 KB/block) bounds
    // occupancy at 2 blocks/CU -> 2 waves/EU -> RA pressure budget 256 VGPR.
    // Never accessed; asm reference keeps it allocated.
    __shared__ char lds_force[60 * 1024];
    asm volatile("" :: "v"((unsigned int)(size_t)lds_force));

    // Weight slice for this wave/lane: W[h][d0+i][e], i=0..15.
    const float* Wc_p = sw + (size_t)h * 4096 + (size_t)d0 * 64 + e;
    const float* Wf_p = Wc_p + (size_t)16 * 4096;
    const float* Wr_p = Wc_p + (size_t)32 * 4096;

    // 48 named scalar weights, pinned into VGPRs (opaque to remat/sink).
    #define DECLW(i) float wc##i, wf##i, wr##i;
    RPT16(DECLW)
    #undef DECLW
    #define LOADW(i) wc##i = Wc_p[(i) * 64]; \
                     wf##i = Wf_p[(i) * 64]; \
                     wr##i = Wr_p[(i) * 64];
    RPT16(LOADW)
    #undef LOADW
    #define PINW(i) asm volatile("" : "+v"(wc##i), "+v"(wf##i), "+v"(wr##i));
    RPT16(PINW)
    #undef PINW

    bf16* xi_p = proj + (size_t)b * S_ * PROJ4 + h * 64 + e;   // cols [0:1024)

    // Register prefetch ring, 4 steps deep, every wave its own copy.
    f32x4 rxi, rxf, rxr;
    #define PRELOAD(U) { const bf16* p = xi_p + (size_t)(U) * PROJ4; \
        rxi[U] = __bfloat162float(p[0]); \
        rxf[U] = __bfloat162float(p[1024]); \
        rxr[U] = __bfloat162float(p[2048]); }
    PRELOAD(0) PRELOAD(1) PRELOAD(2) PRELOAD(3)
    #undef PRELOAD

    float hreg = 0.0f;   // lane e holds h[e]; identical in all 4 waves

    const bf16* ld = xi_p + (size_t)4 * PROJ4;  // refill ptr (t+4)
    bf16*       st = xi_p;                      // store ptr (t)

    // P1 term: broadcast h[d0+i], accumulate r and f gate partials.
    #define P1T(i, A) { float hb = lane_bcast(hreg, d0 + (i)); \
        aR##A = fmaf(hb, wr##i, aR##A); \
        aF##A = fmaf(hb, wf##i, aF##A); }
    // P2 term: broadcast rh[d0+i], accumulate c partial.
    #define P2T(i, A) { float qb = lane_bcast(rh, d0 + (i)); \
        aC##A = fmaf(qb, wc##i, aC##A); }

    #define STEP(U, REFILL) { \
        float xi0 = rxi[U], xf0 = rxf[U], xr0 = rxr[U]; \
        if (REFILL) { \
            const bf16* p = ld + (size_t)(U) * PROJ4; \
            rxi[U] = __bfloat162float(p[0]); \
            rxf[U] = __bfloat162float(p[1024]); \
            rxr[U] = __bfloat162float(p[2048]); \
        } \
        float aR0 = 0.f, aR1 = 0.f, aF0 = 0.f, aF1 = 0.f; \
        P1T(0,0)  P1T(1,1)  P1T(2,0)  P1T(3,1) \
        P1T(4,0)  P1T(5,1)  P1T(6,0)  P1T(7,1) \
        P1T(8,0)  P1T(9,1)  P1T(10,0) P1T(11,1) \
        P1T(12,0) P1T(13,1) P1T(14,0) P1T(15,1) \
        part_rf[w][e] = make_float2(aR0 + aR1, aF0 + aF1); \
        BARRIER_LGKM(); \
        float2 p0 = part_rf[0][e], p1 = part_rf[1][e]; \
        float2 p2 = part_rf[2][e], p3 = part_rf[3][e]; \
        float sr = xr0 + (p0.x + p1.x) + (p2.x + p3.x); \
        float sf = xf0 + (p0.y + p1.y) + (p2.y + p3.y); \
        float r = 1.f / (1.f + __expf(-sr)); \
        float f = 1.f / (1.f + __expf(-sf)); \
        float rh = r * hreg; \
        float aC0 = 0.f, aC1 = 0.f; \
        P2T(0,0)  P2T(1,1)  P2T(2,0)  P2T(3,1) \
        P2T(4,0)  P2T(5,1)  P2T(6,0)  P2T(7,1) \
        P2T(8,0)  P2T(9,1)  P2T(10,0) P2T(11,1) \
        P2T(12,0) P2T(13,1) P2T(14,0) P2T(15,1) \
        part_c[w][e] = aC0 + aC1; \
        BARRIER_LGKM(); \
        float sc = xi0 + (part_c[0][e] + part_c[1][e]) \
                       + (part_c[2][e] + part_c[3][e]); \
        sc = fminf(fmaxf(sc, -15.f), 15.f); \
        float ex = __expf(-2.f * sc); \
        float cc = (1.f - ex) / (1.f + ex); \
        hreg = f * hreg + (1.f - f) * cc; \
        if (w == (U)) st[(size_t)(U) * PROJ4] = __float2bfloat16(hreg); \
    }

    for (int t0 = 0; t0 < S_ - 4; t0 += 4) {
        STEP(0, 1) STEP(1, 1) STEP(2, 1) STEP(3, 1)
        ld += (size_t)4 * PROJ4;
        st += (size_t)4 * PROJ4;
    }
    STEP(0, 0) STEP(1, 0) STEP(2, 0) STEP(3, 0)

    #undef STEP
    #undef P1T
    #undef P2T
}

// ---------------------------------------------------------------------------
// Gated RMSNorm in place over proj cols [0:1024).
// ---------------------------------------------------------------------------
__global__ __launch_bounds__(256) void gate_norm_kernel(bf16* __restrict__ proj,
                                                        const float* __restrict__ nw) {
    const int row = blockIdx.x;
    const int tid = threadIdx.x;
    __shared__ float red[4];

    bf16* hp = proj + (size_t)row * PROJ4;
    const bf16* gp = hp + 3 * DSTATE;

    float4 hv = load4(hp + tid * 4);
    float4 gv = load4(gp + tid * 4);

    float v0 = hv.x * (gv.x / (1.f + __expf(-gv.x)));
    float v1 = hv.y * (gv.y / (1.f + __expf(-gv.y)));
    float v2 = hv.z * (gv.z / (1.f + __expf(-gv.z)));
    float v3 = hv.w * (gv.w / (1.f + __expf(-gv.w)));

    float ss = v0 * v0 + v1 * v1 + v2 * v2 + v3 * v3;
    #pragma unroll
    for (int mask = 32; mask >= 1; mask >>= 1)
        ss += __shfl_xor(ss, mask, 64);

    const int wid = tid >> 6;
    if ((tid & 63) == 0) red[wid] = ss;
    __syncthreads();
    float tot = red[0] + red[1] + red[2] + red[3];
    float scale = rsqrtf(tot * (1.0f / (float)DSTATE) + 1e-6f);

    float4 nv = *(const float4*)(nw + tid * 4);
    float4 y;
    y.x = v0 * scale * nv.x;
    y.y = v1 * scale * nv.y;
    y.z = v2 * scale * nv.z;
    y.w = v3 * scale * nv.w;
    store4(hp + tid * 4, y);
}

// ---------------------------------------------------------------------------
extern "C" void kernel_launch(void* const* d_in, const int* in_sizes, int n_in,
                              void* d_out, int out_size, void* d_ws, size_t ws_size,
                              hipStream_t stream) {
    const float* x     = (const float*)d_in[0];   // [B,S,DIN]
    const float* w_in  = (const float*)d_in[1];   // [DIN, 4*DSTATE]
    const float* sw    = (const float*)d_in[2];   // [3H, DH, DH]
    const float* nw    = (const float*)d_in[3];   // [DSTATE]
    const float* w_out = (const float*)d_in[4];   // [DSTATE, DOUT]
    float* out = (float*)d_out;

    bf16* proj = (bf16*)d_ws;    // [B*S, 4096] bf16 = 134 MB (only ws use)

    // 1) input projection GEMM (MFMA bf16): [16384,1024] @ [1024,4096] -> bf16
    dim3 g1(PROJ4 / 128, (B_ * S_) / 128);
    gemm_mfma<float, bf16><<<g1, 256, 0, stream>>>(x, w_in, proj,
                                                   B_ * S_, PROJ4, DIN, DIN);

    // 2) sequential gated recurrence: 4 waves/chain, pinned weights,
    //    LDS-padded to force a relaxed RA pressure target
    recur_kernel<<<128, 256, 0, stream>>>(proj, sw);

    // 3) gate + rmsnorm in place over cols 0:1024
    gate_norm_kernel<<<B_ * S_, 256, 0, stream>>>(proj, nw);

    // 4) output projection GEMM (MFMA bf16): y(bf16, lda=4096) @ [1024,1024] -> f32
    dim3 g2(DSTATE / 128, (B_ * S_) / 128);
    gemm_mfma<bf16, float><<<g2, 256, 0, stream>>>(proj, w_out, out,
                                                   B_ * S_, DSTATE, DSTATE, PROJ4);
}